// Round 18
// baseline (1531.677 us; speedup 1.0000x reference)
//
#include <hip/hip_runtime.h>
#include <math.h>

#define B_ 16
#define N_ 16384
#define C_ 256
#define H_ 128
#define K_ 11468   // int(16384 * 0.7)
#define G_ ((B_ * N_) / 16)   // 16384 groups of 16 tokens
#define GPB_ 16               // groups per block
#define NBLK_ (G_ / GPB_)     // 1024 blocks

// ---- DIAGNOSTIC ROUND: idempotent repeat loops lift each kernel above the
// ~156us ws-poison fills so rocprof's top-5 finally shows OUR counters.
// Outputs are bit-identical to round 16 (every rep rewrites the same values).
#define REP_SCORE 3
#define REP_GATHER 3
#define REP_SELECT 32

typedef __attribute__((ext_vector_type(8))) short s16x8;
typedef __attribute__((ext_vector_type(4))) float f32x4;
typedef __attribute__((ext_vector_type(4))) unsigned int u32x4;

__device__ __forceinline__ unsigned short f2bf(float f) {
  unsigned u = __builtin_bit_cast(unsigned, f);
  return (unsigned short)((u + 0x7FFFu + ((u >> 16) & 1u)) >> 16);  // RNE
}
__device__ __forceinline__ unsigned fkey(float f) {
  unsigned u = __builtin_bit_cast(unsigned, f);
  return (u & 0x80000000u) ? ~u : (u | 0x80000000u);
}
__device__ __forceinline__ unsigned pk2(float hi, float lo) {
  return __builtin_amdgcn_perm(__builtin_bit_cast(unsigned, hi),
                               __builtin_bit_cast(unsigned, lo), 0x07060302u);
}

#define LDS_BARRIER()                                     \
  do {                                                    \
    asm volatile("s_waitcnt lgkmcnt(0)" ::: "memory");    \
    __builtin_amdgcn_s_barrier();                         \
  } while (0)

__device__ __forceinline__ float gelu_fast(float h) {
  const float t = 0.5f * h * h;
  const float u = 0.147f * t;
  const float num = t * (1.2732395f + u);
  const float den = 1.0f + u;
  const float r = num * __builtin_amdgcn_rcpf(den);
  const float e = __builtin_amdgcn_exp2f(r * -1.44269504f);
  const float s = __builtin_amdgcn_sqrtf(fmaxf(1.0f - e, 0.0f));
  const unsigned sgn = __builtin_bit_cast(unsigned, h) & 0x80000000u;
  const float erfv = __builtin_bit_cast(float, __builtin_bit_cast(unsigned, s) | sgn);
  return 0.5f * h * (1.0f + erfv);
}

// ---- w1 fp32 [C][H] -> plain bf16 transpose w1t[H][C] ----
__global__ void k_prep(const float* __restrict__ w1, unsigned short* __restrict__ w1t) {
  int i = blockIdx.x * blockDim.x + threadIdx.x;
  if (i < C_ * H_) {
    int c = i / H_, h = i % H_;
    w1t[h * C_ + c] = f2bf(w1[i]);
  }
}

// ---------------- fused scorer (round-16 structure, x REP_SCORE) ----------------
__global__ __launch_bounds__(256) void k_score(
    const float* __restrict__ tokens, const unsigned short* __restrict__ w1t,
    const float* __restrict__ b1, const float* __restrict__ w2,
    const float* __restrict__ b2, float* __restrict__ scores_out) {
  __shared__ unsigned short lds_a[2][8 * 64 * 8];
  __shared__ float lds_c[4][16];

  const int tid = threadIdx.x;
  const int lane = tid & 63;
  const int l15 = lane & 15;
  const int l4 = lane >> 4;
  const int w = tid >> 6;

  s16x8 bfr0[8], bfr1[8];
  const int row0 = (2 * w) * 16 + l15;
  const int row1 = row0 + 16;
#pragma unroll
  for (int kk = 0; kk < 8; ++kk) {
    bfr0[kk] = *reinterpret_cast<const s16x8*>(w1t + row0 * 256 + (l4 + 4 * kk) * 8);
    bfr1[kk] = *reinterpret_cast<const s16x8*>(w1t + row1 * 256 + (l4 + 4 * kk) * 8);
  }
  const float b1v0 = b1[row0], b1v1 = b1[row1];
  const float w2v0 = w2[row0], w2v1 = w2[row1];
  const float b2v = b2[0];

  const int t = tid & 15;
  const int s = tid >> 4;
  const int g0 = blockIdx.x * GPB_;
  const float* tg = tokens + ((size_t)(g0 * 16 + t)) * 256 + s * 16;
  const int lb0 = (2 * s) * 128 + t * 8;
  const int lb1 = lb0 + 128;

#pragma unroll 1
  for (int rep = 0; rep < REP_SCORE; ++rep) {
    f32x4 vv[4];
    {
#pragma unroll
      for (int q = 0; q < 4; ++q) vv[q] = *reinterpret_cast<const f32x4*>(tg + 4 * q);
      u32x4 o0, o1;
      o0[0] = pk2(vv[0][1], vv[0][0]);
      o0[1] = pk2(vv[0][3], vv[0][2]);
      o0[2] = pk2(vv[1][1], vv[1][0]);
      o0[3] = pk2(vv[1][3], vv[1][2]);
      o1[0] = pk2(vv[2][1], vv[2][0]);
      o1[1] = pk2(vv[2][3], vv[2][2]);
      o1[2] = pk2(vv[3][1], vv[3][0]);
      o1[3] = pk2(vv[3][3], vv[3][2]);
      *reinterpret_cast<u32x4*>(&lds_a[0][lb0]) = o0;
      *reinterpret_cast<u32x4*>(&lds_a[0][lb1]) = o1;
    }
    LDS_BARRIER();

    int cur = 0;
    for (int i = 0; i < GPB_; ++i) {
      const int g = g0 + i;
      if (i + 1 < GPB_) {
        const float* p = tg + (size_t)(i + 1) * 4096;
#pragma unroll
        for (int q = 0; q < 4; ++q) vv[q] = *reinterpret_cast<const f32x4*>(p + 4 * q);
      }

      f32x4 acc0 = (f32x4){0.f, 0.f, 0.f, 0.f};
      f32x4 acc1 = (f32x4){0.f, 0.f, 0.f, 0.f};
#pragma unroll
      for (int kk = 0; kk < 8; ++kk) {
        s16x8 a = *reinterpret_cast<const s16x8*>(&lds_a[cur][(kk * 64 + lane) * 8]);
        acc0 = __builtin_amdgcn_mfma_f32_16x16x32_bf16(a, bfr0[kk], acc0, 0, 0, 0);
        acc1 = __builtin_amdgcn_mfma_f32_16x16x32_bf16(a, bfr1[kk], acc1, 0, 0, 0);
      }

      float p4[4];
#pragma unroll
      for (int rr = 0; rr < 4; ++rr) {
        float sp = gelu_fast(acc0[rr] + b1v0) * w2v0 + gelu_fast(acc1[rr] + b1v1) * w2v1;
        sp += __shfl_xor(sp, 1);
        sp += __shfl_xor(sp, 2);
        sp += __shfl_xor(sp, 4);
        sp += __shfl_xor(sp, 8);
        p4[rr] = sp;
      }
      if (l15 == 0) {
#pragma unroll
        for (int rr = 0; rr < 4; ++rr) lds_c[w][l4 * 4 + rr] = p4[rr];
      }
      LDS_BARRIER();  // (A)

      if (tid < 16) {
        scores_out[g * 16 + tid] =
            lds_c[0][tid] + lds_c[1][tid] + lds_c[2][tid] + lds_c[3][tid] + b2v;
      }
      if (i + 1 < GPB_) {
        u32x4 o0, o1;
        o0[0] = pk2(vv[0][1], vv[0][0]);
        o0[1] = pk2(vv[0][3], vv[0][2]);
        o0[2] = pk2(vv[1][1], vv[1][0]);
        o0[3] = pk2(vv[1][3], vv[1][2]);
        o1[0] = pk2(vv[2][1], vv[2][0]);
        o1[1] = pk2(vv[2][3], vv[2][2]);
        o1[2] = pk2(vv[3][1], vv[3][0]);
        o1[3] = pk2(vv[3][3], vv[3][2]);
        *reinterpret_cast<u32x4*>(&lds_a[cur ^ 1][lb0]) = o0;
        *reinterpret_cast<u32x4*>(&lds_a[cur ^ 1][lb1]) = o1;
      }
      LDS_BARRIER();  // (B)
      cur ^= 1;
    }
    asm volatile("" ::: "memory");  // keep reps from collapsing
  }
}

// ---------------- block-wide exclusive scan over 1024 threads ----------------
__device__ unsigned block_exscan_1024(unsigned v, volatile unsigned* wsum) {
  const int lane = threadIdx.x & 63;
  const int w = threadIdx.x >> 6;
  unsigned x = v;
#pragma unroll
  for (int d = 1; d < 64; d <<= 1) {
    unsigned t = __shfl_up(x, d);
    if (lane >= d) x += t;
  }
  if (lane == 63) wsum[w] = x;
  __syncthreads();
  if (threadIdx.x == 0) {
    unsigned s = 0;
    for (int i = 0; i < 16; ++i) {
      unsigned t = wsum[i];
      wsum[i] = s;
      s += t;
    }
  }
  __syncthreads();
  unsigned r = wsum[w] + x - v;
  __syncthreads();
  return r;
}

// ---------------- per-row top-K (x REP_SELECT) ----------------
__global__ __launch_bounds__(1024) void k_select(const float* __restrict__ scores_f,
                                                 int* __restrict__ kept,
                                                 float* __restrict__ out_idx) {
  __shared__ unsigned hist[256];
  __shared__ unsigned wsum[16];
  __shared__ unsigned sh_prefix, sh_rk;
  const int b = blockIdx.x;
  const int tid = threadIdx.x;
  const float* sp = scores_f + (size_t)b * N_;

#pragma unroll 1
  for (int rep = 0; rep < REP_SELECT; ++rep) {
    unsigned prefix = 0;
    unsigned rk = K_;
    for (int pass = 0; pass < 4; ++pass) {
      const int shift = 24 - pass * 8;
      if (tid < 256) hist[tid] = 0;
      __syncthreads();
      const unsigned pmask = pass ? (0xFFFFFFFFu << (shift + 8)) : 0u;
      for (int i = tid; i < N_; i += 1024) {
        unsigned k = fkey(sp[i]);
        if ((k & pmask) == prefix) atomicAdd(&hist[(k >> shift) & 255u], 1u);
      }
      __syncthreads();
      unsigned h = (tid < 256) ? hist[255 - tid] : 0u;
      unsigned s = block_exscan_1024(h, wsum);
      if (tid < 256 && s < rk && s + h >= rk) {
        sh_prefix = prefix | ((unsigned)(255 - tid) << shift);
        sh_rk = rk - s;
      }
      __syncthreads();
      prefix = sh_prefix;
      rk = sh_rk;
      __syncthreads();
    }
    const unsigned Tkey = prefix;
    const unsigned need = rk;

    const int i0 = tid * 16;
    unsigned neq = 0;
    for (int j = 0; j < 16; ++j) {
      unsigned k = fkey(sp[i0 + j]);
      neq += (k == Tkey);
    }
    unsigned eq_base = block_exscan_1024(neq, wsum);

    unsigned kcnt = 0;
    {
      unsigned eqr = eq_base;
      for (int j = 0; j < 16; ++j) {
        unsigned k = fkey(sp[i0 + j]);
        bool kp = (k > Tkey) || ((k == Tkey) && (eqr < need));
        eqr += (k == Tkey);
        kcnt += kp;
      }
    }
    unsigned pos = block_exscan_1024(kcnt, wsum);
    {
      unsigned eqr = eq_base;
      for (int j = 0; j < 16; ++j) {
        unsigned k = fkey(sp[i0 + j]);
        bool kp = (k > Tkey) || ((k == Tkey) && (eqr < need));
        eqr += (k == Tkey);
        if (kp) {
          kept[(size_t)b * K_ + pos] = i0 + j;
          out_idx[(size_t)b * K_ + pos] = (float)(i0 + j);
          ++pos;
        }
      }
    }
    __syncthreads();
    asm volatile("" ::: "memory");
  }
}

// ---------------- gather kept token rows (x REP_GATHER) ----------------
__global__ __launch_bounds__(256) void k_gather(const float* __restrict__ tokens,
                                                const int* __restrict__ kept,
                                                float* __restrict__ outp) {
  const int wid = (blockIdx.x * blockDim.x + threadIdx.x) >> 6;
  const int lane = threadIdx.x & 63;
  if (wid >= B_ * K_) return;
  const int b = wid / K_;
#pragma unroll 1
  for (int rep = 0; rep < REP_GATHER; ++rep) {
    const int idx = kept[wid];
    const f32x4 v =
        *reinterpret_cast<const f32x4*>(tokens + ((size_t)b * N_ + idx) * C_ + lane * 4);
    *reinterpret_cast<f32x4*>(outp + (size_t)wid * C_ + lane * 4) = v;
    asm volatile("" ::: "memory");
  }
}

extern "C" void kernel_launch(void* const* d_in, const int* in_sizes, int n_in,
                              void* d_out, int out_size, void* d_ws, size_t ws_size,
                              hipStream_t stream) {
  const float* tokens = (const float*)d_in[0];
  const float* w1 = (const float*)d_in[1];
  const float* b1 = (const float*)d_in[2];
  const float* w2 = (const float*)d_in[3];
  const float* b2 = (const float*)d_in[4];

  float* out = (float*)d_out;
  float* out_pruned = out;                                  // B*K*C fp32
  float* out_idx = out + (size_t)B_ * K_ * C_;              // B*K fp32
  float* out_scores = out_idx + (size_t)B_ * K_;            // B*N fp32

  char* ws = (char*)d_ws;
  unsigned short* w1t = (unsigned short*)ws;                // 64 KB plain bf16 W1^T
  int* kept = (int*)(ws + 0x10000);                         // B*K int32

  k_prep<<<dim3((C_ * H_ + 255) / 256), dim3(256), 0, stream>>>(w1, w1t);
  k_score<<<dim3(NBLK_), dim3(256), 0, stream>>>(tokens, w1t, b1, w2, b2, out_scores);
  k_select<<<dim3(B_), dim3(1024), 0, stream>>>(out_scores, kept, out_idx);
  k_gather<<<dim3((B_ * K_ + 3) / 4), dim3(256), 0, stream>>>(tokens, kept, out_pruned);
}

// Round 19
// 158.828 us; speedup vs baseline: 9.6436x; 9.6436x over previous
//
#include <hip/hip_runtime.h>
#include <math.h>

#define B_ 16
#define N_ 16384
#define C_ 256
#define H_ 128
#define K_ 11468   // int(16384 * 0.7)
#define G_ ((B_ * N_) / 16)   // 16384 groups of 16 tokens
#define GPB_ 16               // groups per block
#define NBLK_ (G_ / GPB_)     // 1024 blocks

typedef __attribute__((ext_vector_type(8))) short s16x8;
typedef __attribute__((ext_vector_type(4))) float f32x4;
typedef __attribute__((ext_vector_type(4))) unsigned int u32x4;

__device__ __forceinline__ unsigned short f2bf(float f) {
  unsigned u = __builtin_bit_cast(unsigned, f);
  return (unsigned short)((u + 0x7FFFu + ((u >> 16) & 1u)) >> 16);  // RNE
}
// order-preserving map fp32 -> uint32 (no NaNs expected)
__device__ __forceinline__ unsigned fkey(float f) {
  unsigned u = __builtin_bit_cast(unsigned, f);
  return (u & 0x80000000u) ? ~u : (u | 0x80000000u);
}
// pack two fp32 to two bf16 (truncation) in one v_perm — same bits as rounds 4-18
__device__ __forceinline__ unsigned pk2(float hi, float lo) {
  return __builtin_amdgcn_perm(__builtin_bit_cast(unsigned, hi),
                               __builtin_bit_cast(unsigned, lo), 0x07060302u);
}

#define LDS_BARRIER()                                     \
  do {                                                    \
    asm volatile("s_waitcnt lgkmcnt(0)" ::: "memory");    \
    __builtin_amdgcn_s_barrier();                         \
  } while (0)

__device__ __forceinline__ float gelu_fast(float h) {
  const float t = 0.5f * h * h;
  const float u = 0.147f * t;
  const float num = t * (1.2732395f + u);
  const float den = 1.0f + u;
  const float r = num * __builtin_amdgcn_rcpf(den);
  const float e = __builtin_amdgcn_exp2f(r * -1.44269504f);
  const float s = __builtin_amdgcn_sqrtf(fmaxf(1.0f - e, 0.0f));
  const unsigned sgn = __builtin_bit_cast(unsigned, h) & 0x80000000u;
  const float erfv = __builtin_bit_cast(float, __builtin_bit_cast(unsigned, s) | sgn);
  return 0.5f * h * (1.0f + erfv);
}

// ---- w1 fp32 [C][H] -> plain bf16 transpose w1t[H][C] ----
__global__ void k_prep(const float* __restrict__ w1, unsigned short* __restrict__ w1t) {
  int i = blockIdx.x * blockDim.x + threadIdx.x;
  if (i < C_ * H_) {
    int c = i / H_, h = i % H_;
    w1t[h * C_ + c] = f2bf(w1[i]);
  }
}

// ---------------- fused scorer (round-16 structure, unchanged) ----------------
__global__ __launch_bounds__(256) void k_score(
    const float* __restrict__ tokens, const unsigned short* __restrict__ w1t,
    const float* __restrict__ b1, const float* __restrict__ w2,
    const float* __restrict__ b2, float* __restrict__ scores_out) {
  __shared__ unsigned short lds_a[2][8 * 64 * 8];
  __shared__ float lds_c[4][16];

  const int tid = threadIdx.x;
  const int lane = tid & 63;
  const int l15 = lane & 15;
  const int l4 = lane >> 4;
  const int w = tid >> 6;

  s16x8 bfr0[8], bfr1[8];
  const int row0 = (2 * w) * 16 + l15;
  const int row1 = row0 + 16;
#pragma unroll
  for (int kk = 0; kk < 8; ++kk) {
    bfr0[kk] = *reinterpret_cast<const s16x8*>(w1t + row0 * 256 + (l4 + 4 * kk) * 8);
    bfr1[kk] = *reinterpret_cast<const s16x8*>(w1t + row1 * 256 + (l4 + 4 * kk) * 8);
  }
  const float b1v0 = b1[row0], b1v1 = b1[row1];
  const float w2v0 = w2[row0], w2v1 = w2[row1];
  const float b2v = b2[0];

  const int t = tid & 15;
  const int s = tid >> 4;
  const int g0 = blockIdx.x * GPB_;
  const float* tg = tokens + ((size_t)(g0 * 16 + t)) * 256 + s * 16;
  const int lb0 = (2 * s) * 128 + t * 8;
  const int lb1 = lb0 + 128;

  f32x4 vv[4];
  {
#pragma unroll
    for (int q = 0; q < 4; ++q) vv[q] = *reinterpret_cast<const f32x4*>(tg + 4 * q);
    u32x4 o0, o1;
    o0[0] = pk2(vv[0][1], vv[0][0]);
    o0[1] = pk2(vv[0][3], vv[0][2]);
    o0[2] = pk2(vv[1][1], vv[1][0]);
    o0[3] = pk2(vv[1][3], vv[1][2]);
    o1[0] = pk2(vv[2][1], vv[2][0]);
    o1[1] = pk2(vv[2][3], vv[2][2]);
    o1[2] = pk2(vv[3][1], vv[3][0]);
    o1[3] = pk2(vv[3][3], vv[3][2]);
    *reinterpret_cast<u32x4*>(&lds_a[0][lb0]) = o0;
    *reinterpret_cast<u32x4*>(&lds_a[0][lb1]) = o1;
  }
  LDS_BARRIER();

  int cur = 0;
  for (int i = 0; i < GPB_; ++i) {
    const int g = g0 + i;
    if (i + 1 < GPB_) {
      const float* p = tg + (size_t)(i + 1) * 4096;
#pragma unroll
      for (int q = 0; q < 4; ++q) vv[q] = *reinterpret_cast<const f32x4*>(p + 4 * q);
    }

    f32x4 acc0 = (f32x4){0.f, 0.f, 0.f, 0.f};
    f32x4 acc1 = (f32x4){0.f, 0.f, 0.f, 0.f};
#pragma unroll
    for (int kk = 0; kk < 8; ++kk) {
      s16x8 a = *reinterpret_cast<const s16x8*>(&lds_a[cur][(kk * 64 + lane) * 8]);
      acc0 = __builtin_amdgcn_mfma_f32_16x16x32_bf16(a, bfr0[kk], acc0, 0, 0, 0);
      acc1 = __builtin_amdgcn_mfma_f32_16x16x32_bf16(a, bfr1[kk], acc1, 0, 0, 0);
    }

    float p4[4];
#pragma unroll
    for (int rr = 0; rr < 4; ++rr) {
      float sp = gelu_fast(acc0[rr] + b1v0) * w2v0 + gelu_fast(acc1[rr] + b1v1) * w2v1;
      sp += __shfl_xor(sp, 1);
      sp += __shfl_xor(sp, 2);
      sp += __shfl_xor(sp, 4);
      sp += __shfl_xor(sp, 8);
      p4[rr] = sp;
    }
    if (l15 == 0) {
#pragma unroll
      for (int rr = 0; rr < 4; ++rr) lds_c[w][l4 * 4 + rr] = p4[rr];
    }
    LDS_BARRIER();  // (A)

    if (tid < 16) {
      scores_out[g * 16 + tid] =
          lds_c[0][tid] + lds_c[1][tid] + lds_c[2][tid] + lds_c[3][tid] + b2v;
    }
    if (i + 1 < GPB_) {
      u32x4 o0, o1;
      o0[0] = pk2(vv[0][1], vv[0][0]);
      o0[1] = pk2(vv[0][3], vv[0][2]);
      o0[2] = pk2(vv[1][1], vv[1][0]);
      o0[3] = pk2(vv[1][3], vv[1][2]);
      o1[0] = pk2(vv[2][1], vv[2][0]);
      o1[1] = pk2(vv[2][3], vv[2][2]);
      o1[2] = pk2(vv[3][1], vv[3][0]);
      o1[3] = pk2(vv[3][3], vv[3][2]);
      *reinterpret_cast<u32x4*>(&lds_a[cur ^ 1][lb0]) = o0;
      *reinterpret_cast<u32x4*>(&lds_a[cur ^ 1][lb1]) = o1;
    }
    LDS_BARRIER();  // (B)
    cur ^= 1;
  }
}

// ---- block exscan over 1024 threads; wave-parallel cross-wave scan (no serial loop)
__device__ unsigned block_exscan_1024(unsigned v, volatile unsigned* wsum) {
  const int tid = threadIdx.x;
  const int lane = tid & 63;
  const int w = tid >> 6;  // 0..15
  unsigned x = v;
#pragma unroll
  for (int d = 1; d < 64; d <<= 1) {
    unsigned t = __shfl_up(x, d);
    if (lane >= d) x += t;
  }
  if (lane == 63) wsum[w] = x;
  __syncthreads();
  if (tid < 16) {
    unsigned s = wsum[tid];
#pragma unroll
    for (int d = 1; d < 16; d <<= 1) {
      unsigned u = __shfl_up(s, d);
      if (tid >= d) s += u;
    }
    wsum[tid] = s;  // inclusive wave sums
  }
  __syncthreads();
  unsigned r = (w ? wsum[w - 1] : 0u) + x - v;  // exclusive
  __syncthreads();  // protect wsum for the next call
  return r;
}

// ---------------- per-row top-K: 3-pass radix (11/11/10) + fused compaction ----------------
__global__ __launch_bounds__(1024) void k_select(const float* __restrict__ scores_f,
                                                 int* __restrict__ kept,
                                                 float* __restrict__ out_idx) {
  __shared__ unsigned hist[2048];   // 8 KB
  __shared__ unsigned wsum[16];
  __shared__ unsigned sh_T, sh_need;
  const int b = blockIdx.x;
  const int tid = threadIdx.x;
  const float* sp = scores_f + (size_t)b * N_;

  // ---- pass 0: bits [31:21] (11 bits, 2048 bins)
  hist[tid] = 0; hist[tid + 1024] = 0;
  __syncthreads();
  for (int i = tid; i < N_; i += 1024) atomicAdd(&hist[fkey(sp[i]) >> 21], 1u);
  __syncthreads();
  {
    const int hi = 2047 - 2 * tid, lo = hi - 1;
    const unsigned chi = hist[hi], pair = chi + hist[lo];
    unsigned before = block_exscan_1024(pair, wsum);  // keys in bins > hi
    if (before < K_ && before + chi >= K_) { sh_T = (unsigned)hi; sh_need = K_ - before; }
    else if (before + chi < K_ && before + pair >= K_) { sh_T = (unsigned)lo; sh_need = K_ - before - chi; }
  }
  __syncthreads();
  const unsigned T0 = sh_T;
  unsigned needK = sh_need;
  __syncthreads();

  // ---- pass 1: bits [20:10] among keys with top11 == T0
  hist[tid] = 0; hist[tid + 1024] = 0;
  __syncthreads();
  for (int i = tid; i < N_; i += 1024) {
    unsigned k = fkey(sp[i]);
    if ((k >> 21) == T0) atomicAdd(&hist[(k >> 10) & 2047u], 1u);
  }
  __syncthreads();
  {
    const int hi = 2047 - 2 * tid, lo = hi - 1;
    const unsigned chi = hist[hi], pair = chi + hist[lo];
    unsigned before = block_exscan_1024(pair, wsum);
    if (before < needK && before + chi >= needK) { sh_T = (unsigned)hi; sh_need = needK - before; }
    else if (before + chi < needK && before + pair >= needK) { sh_T = (unsigned)lo; sh_need = needK - before - chi; }
  }
  __syncthreads();
  const unsigned P21 = (T0 << 11) | sh_T;   // 21-bit prefix
  needK = sh_need;
  __syncthreads();

  // ---- pass 2: bits [9:0] among keys with top21 == P21 (1024 bins, 1/thread)
  hist[tid] = 0;
  __syncthreads();
  for (int i = tid; i < N_; i += 1024) {
    unsigned k = fkey(sp[i]);
    if ((k >> 10) == P21) atomicAdd(&hist[k & 1023u], 1u);
  }
  __syncthreads();
  {
    const int hi = 1023 - tid;
    const unsigned chi = hist[hi];
    unsigned before = block_exscan_1024(chi, wsum);
    if (before < needK && before + chi >= needK) { sh_T = (unsigned)hi; sh_need = needK - before; }
  }
  __syncthreads();
  const unsigned Tkey = (P21 << 10) | sh_T;   // exact K-th largest key
  const unsigned need = sh_need;              // #(==Tkey) kept, lowest index first
  __syncthreads();

  // ---- fused stable compaction: one packed exscan
  const int i0 = tid * 16;
  unsigned cgt = 0, ceq = 0;
  for (int j = 0; j < 16; ++j) {
    unsigned k = fkey(sp[i0 + j]);
    cgt += (k > Tkey);
    ceq += (k == Tkey);
  }
  unsigned packed = block_exscan_1024((cgt << 16) | ceq, wsum);
  unsigned gt_b = packed >> 16;
  unsigned eq_b = packed & 0xFFFFu;
  for (int j = 0; j < 16; ++j) {
    unsigned k = fkey(sp[i0 + j]);
    if (k > Tkey) {
      unsigned pos = gt_b + (eq_b < need ? eq_b : need);
      kept[(size_t)b * K_ + pos] = i0 + j;
      out_idx[(size_t)b * K_ + pos] = (float)(i0 + j);
      ++gt_b;
    } else if (k == Tkey) {
      if (eq_b < need) {
        unsigned pos = gt_b + eq_b;
        kept[(size_t)b * K_ + pos] = i0 + j;
        out_idx[(size_t)b * K_ + pos] = (float)(i0 + j);
      }
      ++eq_b;
    }
  }
}

// ---------------- gather kept token rows (fp32 -> fp32) ----------------
__global__ __launch_bounds__(256) void k_gather(const float* __restrict__ tokens,
                                                const int* __restrict__ kept,
                                                float* __restrict__ outp) {
  const int wid = (blockIdx.x * blockDim.x + threadIdx.x) >> 6;  // one wave per row
  const int lane = threadIdx.x & 63;
  if (wid >= B_ * K_) return;
  const int b = wid / K_;
  const int idx = kept[wid];
  const f32x4 v = *reinterpret_cast<const f32x4*>(tokens + ((size_t)b * N_ + idx) * C_ + lane * 4);
  *reinterpret_cast<f32x4*>(outp + (size_t)wid * C_ + lane * 4) = v;
}

extern "C" void kernel_launch(void* const* d_in, const int* in_sizes, int n_in,
                              void* d_out, int out_size, void* d_ws, size_t ws_size,
                              hipStream_t stream) {
  const float* tokens = (const float*)d_in[0];
  const float* w1 = (const float*)d_in[1];
  const float* b1 = (const float*)d_in[2];
  const float* w2 = (const float*)d_in[3];
  const float* b2 = (const float*)d_in[4];

  float* out = (float*)d_out;
  float* out_pruned = out;                                  // B*K*C fp32
  float* out_idx = out + (size_t)B_ * K_ * C_;              // B*K fp32
  float* out_scores = out_idx + (size_t)B_ * K_;            // B*N fp32

  char* ws = (char*)d_ws;
  unsigned short* w1t = (unsigned short*)ws;                // 64 KB plain bf16 W1^T
  int* kept = (int*)(ws + 0x10000);                         // B*K int32

  k_prep<<<dim3((C_ * H_ + 255) / 256), dim3(256), 0, stream>>>(w1, w1t);
  k_score<<<dim3(NBLK_), dim3(256), 0, stream>>>(tokens, w1t, b1, w2, b2, out_scores);
  k_select<<<dim3(B_), dim3(1024), 0, stream>>>(out_scores, kept, out_idx);
  k_gather<<<dim3((B_ * K_ + 3) / 4), dim3(256), 0, stream>>>(tokens, kept, out_pruned);
}